// Round 8
// baseline (148.256 us; speedup 1.0000x reference)
//
#include <hip/hip_runtime.h>
#include <hip/hip_bf16.h>
#include <math.h>

// Problem constants
#define DM 1024    // d_model
#define DS 16      // d_state
#define BB 4       // batch
#define LL 2048    // seq len
#define LC 32      // scan chunk length
#define NC (LL/LC) // 64 chunks
#define MT 8192    // B*L tokens
#define NCT 17     // GEMM col tiles (16 dt + 1 B/C)
#define KH 512     // K half staged in LDS

typedef __attribute__((ext_vector_type(8))) short short8;
typedef __attribute__((ext_vector_type(4))) float floatx4;

__device__ __forceinline__ float softplus_fast(float v) {
  // max(v,0) + log(1+exp(-|v|)); abs err ~1e-6, negligible vs bf16 storage
  return fmaxf(v, 0.f) + __logf(1.f + __expf(-fabsf(v)));
}

// ---- Kernel 1: pure streaming convert: X->Xb, [W_dt;W_B;W_C;0]->Wx (bf16) ----
__global__ __launch_bounds__(256) void convert_kernel(
    const float* __restrict__ X, const float* __restrict__ W_dt,
    const float* __restrict__ WB, const float* __restrict__ WC,
    __hip_bfloat16* __restrict__ Xb, __hip_bfloat16* __restrict__ Wx)
{
  const size_t i  = (size_t)blockIdx.x * 256 + threadIdx.x;
  const size_t NX = (size_t)MT * DM / 8;   // 1048576
  const size_t NW = (size_t)DM * DM / 8;   //  131072
  const size_t NB = (size_t)DS * DM / 8;   //    2048
  const float* src;
  __hip_bfloat16* dst;
  size_t u;
  if (i < NX)                { src = X;    dst = Xb;                        u = i; }
  else if (i < NX + NW)      { src = W_dt; dst = Wx;                        u = i - NX; }
  else if (i < NX + NW + NB) { src = WB;   dst = Wx + (size_t)1024 * DM;    u = i - NX - NW; }
  else if (i < NX + NW + 2 * NB) { src = WC; dst = Wx + (size_t)1040 * DM;  u = i - NX - NW - NB; }
  else {
    const size_t z = i - NX - NW - 2 * NB;   // 0..4095 -> pad rows 1056..1087
    const short8 zz = {0, 0, 0, 0, 0, 0, 0, 0};
    *(short8*)&Wx[(size_t)1056 * DM + z * 8] = zz;
    return;
  }
  const float4 a = *(const float4*)&src[u * 8];
  const float4 b = *(const float4*)&src[u * 8 + 4];
  union { short8 v; __hip_bfloat16 h[8]; } o;
  o.h[0] = __float2bfloat16(a.x); o.h[1] = __float2bfloat16(a.y);
  o.h[2] = __float2bfloat16(a.z); o.h[3] = __float2bfloat16(a.w);
  o.h[4] = __float2bfloat16(b.x); o.h[5] = __float2bfloat16(b.y);
  o.h[6] = __float2bfloat16(b.z); o.h[7] = __float2bfloat16(b.w);
  *(short8*)&dst[u * 8] = o.v;
}

// ---- Kernel 2: [DT | Bp | Cp] = Xb @ Wx^T, W-RESIDENT-LDS MFMA ----
// Block = 512 thr (8 waves), owns 256 rows x 64 cols. W col-panel staged in LDS
// in two K-halves (64KB, swizzled chunks); K-loop is BARRIER-FREE: A streams
// global->reg (read-once, 1-deep reg dbuf), B from LDS. 4 barriers/block total.
// Grid 544 = 17 ct x 32 rg = 8 XCDs x 68 (bijective swizzle).
__global__ __launch_bounds__(512, 4) void gemm_dt_mfma(
    const __hip_bfloat16* __restrict__ Xb, const __hip_bfloat16* __restrict__ Wx,
    const float* __restrict__ bias, __hip_bfloat16* __restrict__ DTb,
    float* __restrict__ BP, float* __restrict__ CP)
{
  __shared__ short Ws[64 * KH];   // 64KB: [col][k-half], 16B chunks swizzled p^(c&7)
  const int tid  = threadIdx.x;   // 0..511
  const int lane = tid & 63;
  const int wid  = tid >> 6;      // 0..7
  const int fr   = lane & 15;
  const int ks   = lane >> 4;

  const int bid = blockIdx.x;
  const int T   = (bid & 7) * 68 + (bid >> 3);   // bijective: 544 = 8*68
  const int rg  = T / NCT, ct = T % NCT;
  const int row0 = rg * 256;
  const int col0 = ct * 64;
  const int wrow = row0 + wid * 32;              // wave's 32 rows

  const floatx4 zero = {0.f, 0.f, 0.f, 0.f};
  floatx4 acc[2][4];
#pragma unroll
  for (int i = 0; i < 2; ++i)
#pragma unroll
    for (int j = 0; j < 4; ++j) acc[i][j] = zero;

  // stage one K-half of the W panel: 4096 chunks of 16B, 8 per thread.
  // LDS dest linear; source chunk pre-swizzled (rule 21 involution).
  auto STAGEW = [&](int half) {
    const int k0 = half * KH;
#pragma unroll
    for (int q = 0; q < 8; ++q) {
      const int fe = q * 512 + tid;   // chunk id 0..4095
      const int c  = fe >> 6;         // col 0..63
      const int p  = fe & 63;         // LDS chunk position in row
      const int sc = p ^ (c & 7);     // swizzled source chunk
      __builtin_amdgcn_global_load_lds(
          (const __attribute__((address_space(1))) void*)&Wx[(size_t)(col0 + c) * DM + k0 + sc * 8],
          (__attribute__((address_space(3))) void*)&Ws[fe * 8], 16, 0, 0);
    }
  };

  // A fragment loads: lane reads row wrow + i*16 + fr, k = t*32 + ks*8
  const __hip_bfloat16* pa = &Xb[(size_t)(wrow + fr) * DM + ks * 8];
  short8 a0[2], a1[2], bf[4];
  auto LA0 = [&](int t) {
#pragma unroll
    for (int i = 0; i < 2; ++i) a0[i] = *(const short8*)&pa[(size_t)(i * 16) * DM + t * 32];
  };
  auto LA1 = [&](int t) {
#pragma unroll
    for (int i = 0; i < 2; ++i) a1[i] = *(const short8*)&pa[(size_t)(i * 16) * DM + t * 32];
  };
  // B fragment read from LDS, step s within half (0..15)
  auto BREAD = [&](int s) {
#pragma unroll
    for (int j = 0; j < 4; ++j) {
      const int c = j * 16 + fr;
      const int q = s * 4 + ks;
      const int p = q ^ (c & 7);
      bf[j] = *(const short8*)&Ws[c * KH + p * 8];
    }
  };

  STAGEW(0);
  LA0(0);
  asm volatile("s_waitcnt vmcnt(0)" ::: "memory");
  __builtin_amdgcn_s_barrier();

  // half 0: t = 0..15, no barriers
  for (int t = 0; t < 16; t += 2) {
    LA1(t + 1);
    BREAD(t);
#pragma unroll
    for (int i = 0; i < 2; ++i)
#pragma unroll
      for (int j = 0; j < 4; ++j)
        acc[i][j] = __builtin_amdgcn_mfma_f32_16x16x32_bf16(a0[i], bf[j], acc[i][j], 0, 0, 0);
    LA0(t + 2);                 // t+2 <= 16: k = (t+2)*32 valid (A is full-K)
    BREAD(t + 1);
#pragma unroll
    for (int i = 0; i < 2; ++i)
#pragma unroll
      for (int j = 0; j < 4; ++j)
        acc[i][j] = __builtin_amdgcn_mfma_f32_16x16x32_bf16(a1[i], bf[j], acc[i][j], 0, 0, 0);
  }

  // half boundary: restage W
  __builtin_amdgcn_s_barrier();           // all waves done reading half 0
  STAGEW(1);
  asm volatile("s_waitcnt vmcnt(0)" ::: "memory");
  __builtin_amdgcn_s_barrier();

  // half 1: t = 16..31
  for (int t = 16; t < 32; t += 2) {
    LA1(t + 1);
    BREAD(t - 16);
#pragma unroll
    for (int i = 0; i < 2; ++i)
#pragma unroll
      for (int j = 0; j < 4; ++j)
        acc[i][j] = __builtin_amdgcn_mfma_f32_16x16x32_bf16(a0[i], bf[j], acc[i][j], 0, 0, 0);
    if (t + 2 < 32) LA0(t + 2);
    BREAD(t - 15);
#pragma unroll
    for (int i = 0; i < 2; ++i)
#pragma unroll
      for (int j = 0; j < 4; ++j)
        acc[i][j] = __builtin_amdgcn_mfma_f32_16x16x32_bf16(a1[i], bf[j], acc[i][j], 0, 0, 0);
  }

  // epilogue. C/D layout: col=lane&15, row=(lane>>4)*4+r
  const int cl = lane & 15;
  const int rg4 = lane >> 4;
  if (ct < 16) {
#pragma unroll
    for (int i = 0; i < 2; ++i) {
#pragma unroll
      for (int r = 0; r < 4; ++r) {
        const size_t row = (size_t)(wrow + i * 16 + rg4 * 4 + r);
#pragma unroll
        for (int j = 0; j < 4; ++j) {
          const int col = col0 + j * 16 + cl;
          const float v = acc[i][j][r] + bias[col];
          DTb[row * DM + col] = __float2bfloat16(softplus_fast(v));
        }
      }
    }
  } else {
    // B/C tile: j==0 -> Bp (cols 1024..1039), j==1 -> Cp (1040..1055), j>=2 pad
#pragma unroll
    for (int i = 0; i < 2; ++i) {
#pragma unroll
      for (int r = 0; r < 4; ++r) {
        const size_t row = (size_t)(wrow + i * 16 + rg4 * 4 + r);
        BP[row * DS + cl] = acc[i][0][r];
        CP[row * DS + cl] = acc[i][1][r];
      }
    }
  }
}

// ---- Kernel 3: per-chunk local scan (pass A), bf16 dt/x inputs ----
// Stores HP (chunk-local end state) and SD (sum of dt over chunk; P=exp(SD*A)).
__global__ __launch_bounds__(256) void scan_partial_kernel(
    const __hip_bfloat16* __restrict__ DT, const __hip_bfloat16* __restrict__ X,
    const float* __restrict__ Bp, const float* __restrict__ A_log,
    float* __restrict__ SD, float* __restrict__ HP)
{
  const int d = blockIdx.x * 256 + threadIdx.x;
  const int c = blockIdx.y;
  const int b = blockIdx.z;
  float A[DS], h[DS];
  float sdt = 0.f;
  const float4* arow = (const float4*)&A_log[(size_t)d * DS];
#pragma unroll
  for (int m = 0; m < 4; ++m) {
    const float4 a4 = arow[m];
    A[m*4+0] = -__expf(a4.x); A[m*4+1] = -__expf(a4.y);
    A[m*4+2] = -__expf(a4.z); A[m*4+3] = -__expf(a4.w);
  }
#pragma unroll
  for (int n = 0; n < DS; ++n) h[n] = 0.f;

  const int l0 = c * LC;
  size_t idx = ((size_t)b * LL + l0) * DM + d;
  const float4* bv = (const float4*)&Bp[((size_t)b * LL + l0) * DS];

  float dtb[4], xb[4];
#pragma unroll
  for (int u = 0; u < 4; ++u) {
    dtb[u] = __bfloat162float(DT[idx + (size_t)u * DM]);
    xb[u]  = __bfloat162float(X[idx + (size_t)u * DM]);
  }

  for (int l = 0; l < LC; l += 4) {
    float dtn[4], xn[4];
    if (l + 4 < LC) {
#pragma unroll
      for (int u = 0; u < 4; ++u) {
        dtn[u] = __bfloat162float(DT[idx + (size_t)(u + 4) * DM]);
        xn[u]  = __bfloat162float(X[idx + (size_t)(u + 4) * DM]);
      }
    }
#pragma unroll
    for (int u = 0; u < 4; ++u) {
      const float dtv = dtb[u], xv = xb[u];
      const float dx = dtv * xv;
      sdt += dtv;
      const float4 b0 = bv[(l+u)*4+0], b1 = bv[(l+u)*4+1];
      const float4 b2 = bv[(l+u)*4+2], b3 = bv[(l+u)*4+3];
      const float bb[DS] = {b0.x,b0.y,b0.z,b0.w, b1.x,b1.y,b1.z,b1.w,
                            b2.x,b2.y,b2.z,b2.w, b3.x,b3.y,b3.z,b3.w};
#pragma unroll
      for (int n = 0; n < DS; ++n) {
        const float dA = __expf(dtv * A[n]);
        h[n] = fmaf(dA, h[n], dx * bb[n]);
      }
    }
    idx += (size_t)4 * DM;
#pragma unroll
    for (int u = 0; u < 4; ++u) { dtb[u] = dtn[u]; xb[u] = xn[u]; }
  }
  SD[((size_t)b * NC + c) * DM + d] = sdt;
  const size_t o = (((size_t)b * NC + c) * DM + d) * DS;
  float4* hp = (float4*)&HP[o];
#pragma unroll
  for (int m = 0; m < 4; ++m)
    hp[m] = make_float4(h[m*4+0], h[m*4+1], h[m*4+2], h[m*4+3]);
}

// ---- Kernel 4: combine chunk prefixes (sequential over NC), in-place HP->Hin ----
__global__ __launch_bounds__(256) void combine_kernel(
    const float* __restrict__ SD, const float* __restrict__ A_log,
    float* HP)
{
  const int idx = blockIdx.x * 256 + threadIdx.x;  // over B*DM*DS = 65536
  const int b  = idx >> 14;
  const int dn = idx & 16383;        // = d*DS + n
  const int d  = dn >> 4;
  const float A = -__expf(A_log[dn]);
  float h = 0.f;
#pragma unroll 4
  for (int c = 0; c < NC; ++c) {
    const size_t o = (((size_t)b * NC + c) << 14) + dn;
    const float p  = __expf(SD[((size_t)b * NC + c) * DM + d] * A);
    const float hp = HP[o];
    HP[o] = h;              // Hin for chunk c (entry state)
    h = fmaf(p, h, hp);
  }
}

// ---- Kernel 5: final scan + output (pass B), bf16 dt/x inputs ----
__global__ __launch_bounds__(256) void scan_final_kernel(
    const __hip_bfloat16* __restrict__ DT, const __hip_bfloat16* __restrict__ X,
    const float* __restrict__ Bp, const float* __restrict__ Cp,
    const float* __restrict__ A_log, const float* __restrict__ Dvec,
    const float* __restrict__ Hin, float* __restrict__ Y)
{
  const int d = blockIdx.x * 256 + threadIdx.x;
  const int c = blockIdx.y;
  const int b = blockIdx.z;
  float A[DS], h[DS];
  const float4* arow = (const float4*)&A_log[(size_t)d * DS];
  const size_t o = (((size_t)b * NC + c) * DM + d) * DS;
  const float4* hin = (const float4*)&Hin[o];
#pragma unroll
  for (int m = 0; m < 4; ++m) {
    const float4 a4 = arow[m];
    A[m*4+0] = -__expf(a4.x); A[m*4+1] = -__expf(a4.y);
    A[m*4+2] = -__expf(a4.z); A[m*4+3] = -__expf(a4.w);
    const float4 h4 = hin[m];
    h[m*4+0] = h4.x; h[m*4+1] = h4.y; h[m*4+2] = h4.z; h[m*4+3] = h4.w;
  }
  const float Dd = Dvec[d];
  const int l0 = c * LC;
  size_t idx = ((size_t)b * LL + l0) * DM + d;
  const float4* bv = (const float4*)&Bp[((size_t)b * LL + l0) * DS];
  const float4* cv = (const float4*)&Cp[((size_t)b * LL + l0) * DS];

  float dtb[4], xb[4];
#pragma unroll
  for (int u = 0; u < 4; ++u) {
    dtb[u] = __bfloat162float(DT[idx + (size_t)u * DM]);
    xb[u]  = __bfloat162float(X[idx + (size_t)u * DM]);
  }

  for (int l = 0; l < LC; l += 4) {
    float dtn[4], xn[4];
    if (l + 4 < LC) {
#pragma unroll
      for (int u = 0; u < 4; ++u) {
        dtn[u] = __bfloat162float(DT[idx + (size_t)(u + 4) * DM]);
        xn[u]  = __bfloat162float(X[idx + (size_t)(u + 4) * DM]);
      }
    }
#pragma unroll
    for (int u = 0; u < 4; ++u) {
      const float dtv = dtb[u], xv = xb[u];
      const float dx = dtv * xv;
      const float4 b0 = bv[(l+u)*4+0], b1 = bv[(l+u)*4+1];
      const float4 b2 = bv[(l+u)*4+2], b3 = bv[(l+u)*4+3];
      const float bb[DS] = {b0.x,b0.y,b0.z,b0.w, b1.x,b1.y,b1.z,b1.w,
                            b2.x,b2.y,b2.z,b2.w, b3.x,b3.y,b3.z,b3.w};
      const float4 c0 = cv[(l+u)*4+0], c1 = cv[(l+u)*4+1];
      const float4 c2 = cv[(l+u)*4+2], c3 = cv[(l+u)*4+3];
      const float cc[DS] = {c0.x,c0.y,c0.z,c0.w, c1.x,c1.y,c1.z,c1.w,
                            c2.x,c2.y,c2.z,c2.w, c3.x,c3.y,c3.z,c3.w};
      float y = 0.f;
#pragma unroll
      for (int n = 0; n < DS; ++n) {
        const float dA = __expf(dtv * A[n]);
        h[n] = fmaf(dA, h[n], dx * bb[n]);
        y = fmaf(h[n], cc[n], y);
      }
      Y[idx + (size_t)u * DM] = fmaf(Dd, xv, y);
    }
    idx += (size_t)4 * DM;
#pragma unroll
    for (int u = 0; u < 4; ++u) { dtb[u] = dtn[u]; xb[u] = xn[u]; }
  }
}

// ---- launch ----
// Workspace (float slots):
//   DTb : MT*DM bf16   = 4194304
//   BP  : MT*DS        =  131072
//   CP  : MT*DS        =  131072
//   Xb  : MT*DM bf16   = 4194304
//   Wx  : 1088*DM bf16 =  278528
//   SD  : BB*NC*DM     =  262144
//   HP  : BB*NC*DM*DS  = 4194304   (becomes Hin in-place after combine)
// total = 13,385,728 floats = 53,542,912 bytes.
extern "C" void kernel_launch(void* const* d_in, const int* in_sizes, int n_in,
                              void* d_out, int out_size, void* d_ws, size_t ws_size,
                              hipStream_t stream)
{
  const float* x     = (const float*)d_in[0];
  const float* W_dt  = (const float*)d_in[1];
  const float* b_dt  = (const float*)d_in[2];
  const float* W_B   = (const float*)d_in[3];
  const float* W_C   = (const float*)d_in[4];
  const float* A_log = (const float*)d_in[5];
  const float* Dv    = (const float*)d_in[6];
  float* Y  = (float*)d_out;
  float* ws = (float*)d_ws;

  __hip_bfloat16* DTb = (__hip_bfloat16*)ws;
  float* BP = ws + (size_t)MT * DM / 2;
  float* CP = BP + (size_t)MT * DS;
  __hip_bfloat16* Xb = (__hip_bfloat16*)(CP + (size_t)MT * DS);
  __hip_bfloat16* Wx = (__hip_bfloat16*)(CP + (size_t)MT * DS + (size_t)MT * DM / 2);
  float* SD = CP + (size_t)MT * DS + (size_t)MT * DM / 2 + (size_t)1088 * DM / 2;
  float* HP = SD + (size_t)BB * NC * DM;

  convert_kernel<<<4640, 256, 0, stream>>>(x, W_dt, W_B, W_C, Xb, Wx);
  gemm_dt_mfma<<<544, 512, 0, stream>>>(Xb, Wx, b_dt, DTb, BP, CP);
  scan_partial_kernel<<<dim3(DM / 256, NC, BB), 256, 0, stream>>>(DTb, Xb, BP, A_log, SD, HP);
  combine_kernel<<<(BB * DM * DS) / 256, 256, 0, stream>>>(SD, A_log, HP);
  scan_final_kernel<<<dim3(DM / 256, NC, BB), 256, 0, stream>>>(DTb, Xb, BP, CP, A_log, Dv, HP, Y);
}

// Round 9
// 117.057 us; speedup vs baseline: 1.2665x; 1.2665x over previous
//
#include <hip/hip_runtime.h>
#include <hip/hip_bf16.h>
#include <math.h>

// Problem constants
#define DM 1024    // d_model
#define DS 16      // d_state
#define BB 4       // batch
#define LL 2048    // seq len
#define LC 32      // scan chunk length
#define NC (LL/LC) // 64 chunks
#define MT 8192    // B*L tokens
#define NT64 16    // GEMM k-steps (DM/64)
#define NCT 17     // GEMM col tiles (16 dt + 1 B/C)

typedef __attribute__((ext_vector_type(8))) short short8;
typedef __attribute__((ext_vector_type(4))) float floatx4;

__device__ __forceinline__ float softplus_fast(float v) {
  // max(v,0) + log(1+exp(-|v|)); abs err ~1e-6, negligible vs bf16 storage
  return fmaxf(v, 0.f) + __logf(1.f + __expf(-fabsf(v)));
}

// ---- Kernel 1: pure streaming convert: X->Xb, [W_dt;W_B;W_C;0]->Wx (bf16) ----
__global__ __launch_bounds__(256) void convert_kernel(
    const float* __restrict__ X, const float* __restrict__ W_dt,
    const float* __restrict__ WB, const float* __restrict__ WC,
    __hip_bfloat16* __restrict__ Xb, __hip_bfloat16* __restrict__ Wx)
{
  const size_t i  = (size_t)blockIdx.x * 256 + threadIdx.x;
  const size_t NX = (size_t)MT * DM / 8;   // 1048576
  const size_t NW = (size_t)DM * DM / 8;   //  131072
  const size_t NB = (size_t)DS * DM / 8;   //    2048
  const float* src;
  __hip_bfloat16* dst;
  size_t u;
  if (i < NX)                { src = X;    dst = Xb;                        u = i; }
  else if (i < NX + NW)      { src = W_dt; dst = Wx;                        u = i - NX; }
  else if (i < NX + NW + NB) { src = WB;   dst = Wx + (size_t)1024 * DM;    u = i - NX - NW; }
  else if (i < NX + NW + 2 * NB) { src = WC; dst = Wx + (size_t)1040 * DM;  u = i - NX - NW - NB; }
  else {
    const size_t z = i - NX - NW - 2 * NB;   // 0..4095 -> pad rows 1056..1087
    const short8 zz = {0, 0, 0, 0, 0, 0, 0, 0};
    *(short8*)&Wx[(size_t)1056 * DM + z * 8] = zz;
    return;
  }
  const float4 a = *(const float4*)&src[u * 8];
  const float4 b = *(const float4*)&src[u * 8 + 4];
  union { short8 v; __hip_bfloat16 h[8]; } o;
  o.h[0] = __float2bfloat16(a.x); o.h[1] = __float2bfloat16(a.y);
  o.h[2] = __float2bfloat16(a.z); o.h[3] = __float2bfloat16(a.w);
  o.h[4] = __float2bfloat16(b.x); o.h[5] = __float2bfloat16(b.y);
  o.h[6] = __float2bfloat16(b.z); o.h[7] = __float2bfloat16(b.w);
  *(short8*)&dst[u * 8] = o.v;
}

// ---- Kernel 2: [DT | Bp | Cp] = Xb @ Wx^T, MFMA, BK=64, 2-buffer 2-phase ----
// BM=128, BN=64, BK=64; 1088 blocks XCD-swizzled; 4 waves (2x2); 16 MFMA/wave/phase;
// 16 phases. 2 LDS buffers (48KB -> 3 blocks/CU); phase = {STAGE(t+1), ds_read+
// MFMA(t), __syncthreads drain} -- drain overlapped by the other 2 resident blocks.
// 16B-chunk involution swizzle on global source + ds_read (0 conflicts, R7-verified).
__global__ __launch_bounds__(256) void gemm_dt_mfma(
    const __hip_bfloat16* __restrict__ Xb, const __hip_bfloat16* __restrict__ Wx,
    const float* __restrict__ bias, __hip_bfloat16* __restrict__ DTb,
    float* __restrict__ BP, float* __restrict__ CP)
{
  __shared__ short As[2][128 * 64];   // 16KB per buf
  __shared__ short Bs[2][64 * 64];    //  8KB per buf
  const int tid  = threadIdx.x;
  const int lane = tid & 63;
  const int wid  = tid >> 6;        // 0..3
  const int wm   = wid >> 1, wn = wid & 1;

  // XCD swizzle: 1088 blocks = 8 XCDs x 136 (bijective).
  const int bid  = blockIdx.x;
  const int tile = (bid & 7) * 136 + (bid >> 3);
  const int row0 = (tile / NCT) * 128;
  const int col0 = (tile % NCT) * 64;

  const floatx4 zero = {0.f, 0.f, 0.f, 0.f};
  floatx4 acc[4][2];
#pragma unroll
  for (int i = 0; i < 4; ++i)
#pragma unroll
    for (int j = 0; j < 2; ++j) acc[i][j] = zero;

  // STAGE: 6 global_load_lds per thread (4 A + 2 B), 16B each.
  // LDS dest linear; source chunk pre-swizzled (involution kk^(r&7)).
  auto STAGE = [&](int buf, int t) {
    const int k0 = t * 64;
#pragma unroll
    for (int q = 0; q < 4; ++q) {
      const int fe = q * 256 + tid;      // A chunk id 0..1023
      const int r  = fe >> 3;            // row 0..127 (8 chunks/row)
      const int kk = (fe & 7) ^ (r & 7); // swizzled source chunk
      __builtin_amdgcn_global_load_lds(
          (const __attribute__((address_space(1))) void*)&Xb[(size_t)(row0 + r) * DM + k0 + kk * 8],
          (__attribute__((address_space(3))) void*)&As[buf][fe * 8], 16, 0, 0);
    }
#pragma unroll
    for (int q = 0; q < 2; ++q) {
      const int fe = q * 256 + tid;      // B chunk id 0..511
      const int r  = fe >> 3;            // row 0..63
      const int kk = (fe & 7) ^ (r & 7);
      __builtin_amdgcn_global_load_lds(
          (const __attribute__((address_space(1))) void*)&Wx[(size_t)(col0 + r) * DM + k0 + kk * 8],
          (__attribute__((address_space(3))) void*)&Bs[buf][fe * 8], 16, 0, 0);
    }
  };

  const int fr = lane & 15;   // fragment row within 16
  const int ks = lane >> 4;   // k-slice 0..3

  STAGE(0, 0);
  __syncthreads();            // vmcnt(0) drain + barrier (compiler-emitted)

  int cur = 0;
  for (int t = 0; t < NT64; ++t) {
    if (t + 1 < NT64) STAGE(cur ^ 1, t + 1);

    short8 af[4][2], bfr[2][2];
#pragma unroll
    for (int i = 0; i < 4; ++i) {
      const int ar = wm * 64 + i * 16 + fr;
#pragma unroll
      for (int s = 0; s < 2; ++s) {
        const int ch = (ks + 4 * s) ^ (ar & 7);
        af[i][s] = *(const short8*)&As[cur][ar * 64 + ch * 8];
      }
    }
#pragma unroll
    for (int j = 0; j < 2; ++j) {
      const int br = wn * 32 + j * 16 + fr;
#pragma unroll
      for (int s = 0; s < 2; ++s) {
        const int ch = (ks + 4 * s) ^ (br & 7);
        bfr[j][s] = *(const short8*)&Bs[cur][br * 64 + ch * 8];
      }
    }
#pragma unroll
    for (int s = 0; s < 2; ++s)
#pragma unroll
      for (int i = 0; i < 4; ++i)
#pragma unroll
        for (int j = 0; j < 2; ++j)
          acc[i][j] = __builtin_amdgcn_mfma_f32_16x16x32_bf16(af[i][s], bfr[j][s], acc[i][j], 0, 0, 0);

    if (t + 1 < NT64) {
      __syncthreads();        // drains STAGE(t+1) + all waves done reading cur
      cur ^= 1;
    }
  }

  // epilogue. C/D layout: col=lane&15, row=(lane>>4)*4+r
  const int cl = lane & 15;
  const int rg = lane >> 4;
  if (col0 < 1024) {
    // dt path: bias + softplus -> bf16
#pragma unroll
    for (int i = 0; i < 4; ++i) {
#pragma unroll
      for (int r = 0; r < 4; ++r) {
        const size_t row = (size_t)(row0 + wm * 64 + i * 16 + rg * 4 + r);
#pragma unroll
        for (int j = 0; j < 2; ++j) {
          const int col = col0 + wn * 32 + j * 16 + cl;
          const float v = acc[i][j][r] + bias[col];
          DTb[row * DM + col] = __float2bfloat16(softplus_fast(v));
        }
      }
    }
  } else if (wn == 0) {
    // B/C tile: j==0 -> Bp (cols 1024..1039), j==1 -> Cp (1040..1055)
#pragma unroll
    for (int i = 0; i < 4; ++i) {
#pragma unroll
      for (int r = 0; r < 4; ++r) {
        const size_t row = (size_t)(row0 + wm * 64 + i * 16 + rg * 4 + r);
        BP[row * DS + cl] = acc[i][0][r];
        CP[row * DS + cl] = acc[i][1][r];
      }
    }
  }
}

// ---- Kernel 3: per-chunk local scan (pass A), bf16 dt/x inputs ----
// Bp chunk-slab staged in LDS (uniform rows -> broadcast reads).
// Stores HP (chunk-local end state) and SD (sum of dt; P=exp(SD*A)).
__global__ __launch_bounds__(256) void scan_partial_kernel(
    const __hip_bfloat16* __restrict__ DT, const __hip_bfloat16* __restrict__ X,
    const float* __restrict__ Bp, const float* __restrict__ A_log,
    float* __restrict__ SD, float* __restrict__ HP)
{
  __shared__ float sB[LC * DS];   // 2KB: this chunk's Bp rows
  const int tid = threadIdx.x;
  const int d = blockIdx.x * 256 + tid;
  const int c = blockIdx.y;
  const int b = blockIdx.z;
  const int l0 = c * LC;

  if (tid < LC * DS / 4)
    ((float4*)sB)[tid] = ((const float4*)&Bp[((size_t)b * LL + l0) * DS])[tid];

  float A[DS], h[DS];
  float sdt = 0.f;
  const float4* arow = (const float4*)&A_log[(size_t)d * DS];
#pragma unroll
  for (int m = 0; m < 4; ++m) {
    const float4 a4 = arow[m];
    A[m*4+0] = -__expf(a4.x); A[m*4+1] = -__expf(a4.y);
    A[m*4+2] = -__expf(a4.z); A[m*4+3] = -__expf(a4.w);
  }
#pragma unroll
  for (int n = 0; n < DS; ++n) h[n] = 0.f;

  size_t idx = ((size_t)b * LL + l0) * DM + d;
  float dtb[4], xb[4];
#pragma unroll
  for (int u = 0; u < 4; ++u) {
    dtb[u] = __bfloat162float(DT[idx + (size_t)u * DM]);
    xb[u]  = __bfloat162float(X[idx + (size_t)u * DM]);
  }
  __syncthreads();

  for (int l = 0; l < LC; l += 4) {
    float dtn[4], xn[4];
    if (l + 4 < LC) {
#pragma unroll
      for (int u = 0; u < 4; ++u) {
        dtn[u] = __bfloat162float(DT[idx + (size_t)(u + 4) * DM]);
        xn[u]  = __bfloat162float(X[idx + (size_t)(u + 4) * DM]);
      }
    }
#pragma unroll
    for (int u = 0; u < 4; ++u) {
      const float dtv = dtb[u], xv = xb[u];
      const float dx = dtv * xv;
      sdt += dtv;
      const float4 b0 = ((const float4*)sB)[(l+u)*4+0];
      const float4 b1 = ((const float4*)sB)[(l+u)*4+1];
      const float4 b2 = ((const float4*)sB)[(l+u)*4+2];
      const float4 b3 = ((const float4*)sB)[(l+u)*4+3];
      const float bb[DS] = {b0.x,b0.y,b0.z,b0.w, b1.x,b1.y,b1.z,b1.w,
                            b2.x,b2.y,b2.z,b2.w, b3.x,b3.y,b3.z,b3.w};
#pragma unroll
      for (int n = 0; n < DS; ++n) {
        const float dA = __expf(dtv * A[n]);
        h[n] = fmaf(dA, h[n], dx * bb[n]);
      }
    }
    idx += (size_t)4 * DM;
#pragma unroll
    for (int u = 0; u < 4; ++u) { dtb[u] = dtn[u]; xb[u] = xn[u]; }
  }
  SD[((size_t)b * NC + c) * DM + d] = sdt;
  const size_t o = (((size_t)b * NC + c) * DM + d) * DS;
  float4* hp = (float4*)&HP[o];
#pragma unroll
  for (int m = 0; m < 4; ++m)
    hp[m] = make_float4(h[m*4+0], h[m*4+1], h[m*4+2], h[m*4+3]);
}

// ---- Kernel 4: combine chunk prefixes (sequential over NC), in-place HP->Hin ----
__global__ __launch_bounds__(256) void combine_kernel(
    const float* __restrict__ SD, const float* __restrict__ A_log,
    float* HP)
{
  const int idx = blockIdx.x * 256 + threadIdx.x;  // over B*DM*DS = 65536
  const int b  = idx >> 14;
  const int dn = idx & 16383;        // = d*DS + n
  const int d  = dn >> 4;
  const float A = -__expf(A_log[dn]);
  float h = 0.f;
#pragma unroll 4
  for (int c = 0; c < NC; ++c) {
    const size_t o = (((size_t)b * NC + c) << 14) + dn;
    const float p  = __expf(SD[((size_t)b * NC + c) * DM + d] * A);
    const float hp = HP[o];
    HP[o] = h;              // Hin for chunk c (entry state)
    h = fmaf(p, h, hp);
  }
}

// ---- Kernel 5: final scan + output (pass B), bf16 dt/x inputs ----
// Bp AND Cp chunk-slabs staged in LDS.
__global__ __launch_bounds__(256) void scan_final_kernel(
    const __hip_bfloat16* __restrict__ DT, const __hip_bfloat16* __restrict__ X,
    const float* __restrict__ Bp, const float* __restrict__ Cp,
    const float* __restrict__ A_log, const float* __restrict__ Dvec,
    const float* __restrict__ Hin, float* __restrict__ Y)
{
  __shared__ float sB[LC * DS], sC[LC * DS];   // 2KB + 2KB
  const int tid = threadIdx.x;
  const int d = blockIdx.x * 256 + tid;
  const int c = blockIdx.y;
  const int b = blockIdx.z;
  const int l0 = c * LC;

  if (tid < 128)       ((float4*)sB)[tid] = ((const float4*)&Bp[((size_t)b * LL + l0) * DS])[tid];
  else                 ((float4*)sC)[tid - 128] = ((const float4*)&Cp[((size_t)b * LL + l0) * DS])[tid - 128];

  float A[DS], h[DS];
  const float4* arow = (const float4*)&A_log[(size_t)d * DS];
  const size_t o = (((size_t)b * NC + c) * DM + d) * DS;
  const float4* hin = (const float4*)&Hin[o];
#pragma unroll
  for (int m = 0; m < 4; ++m) {
    const float4 a4 = arow[m];
    A[m*4+0] = -__expf(a4.x); A[m*4+1] = -__expf(a4.y);
    A[m*4+2] = -__expf(a4.z); A[m*4+3] = -__expf(a4.w);
    const float4 h4 = hin[m];
    h[m*4+0] = h4.x; h[m*4+1] = h4.y; h[m*4+2] = h4.z; h[m*4+3] = h4.w;
  }
  const float Dd = Dvec[d];
  size_t idx = ((size_t)b * LL + l0) * DM + d;

  float dtb[4], xb[4];
#pragma unroll
  for (int u = 0; u < 4; ++u) {
    dtb[u] = __bfloat162float(DT[idx + (size_t)u * DM]);
    xb[u]  = __bfloat162float(X[idx + (size_t)u * DM]);
  }
  __syncthreads();

  for (int l = 0; l < LC; l += 4) {
    float dtn[4], xn[4];
    if (l + 4 < LC) {
#pragma unroll
      for (int u = 0; u < 4; ++u) {
        dtn[u] = __bfloat162float(DT[idx + (size_t)(u + 4) * DM]);
        xn[u]  = __bfloat162float(X[idx + (size_t)(u + 4) * DM]);
      }
    }
#pragma unroll
    for (int u = 0; u < 4; ++u) {
      const float dtv = dtb[u], xv = xb[u];
      const float dx = dtv * xv;
      const float4 b0 = ((const float4*)sB)[(l+u)*4+0];
      const float4 b1 = ((const float4*)sB)[(l+u)*4+1];
      const float4 b2 = ((const float4*)sB)[(l+u)*4+2];
      const float4 b3 = ((const float4*)sB)[(l+u)*4+3];
      const float bb[DS] = {b0.x,b0.y,b0.z,b0.w, b1.x,b1.y,b1.z,b1.w,
                            b2.x,b2.y,b2.z,b2.w, b3.x,b3.y,b3.z,b3.w};
      const float4 c0 = ((const float4*)sC)[(l+u)*4+0];
      const float4 c1 = ((const float4*)sC)[(l+u)*4+1];
      const float4 c2 = ((const float4*)sC)[(l+u)*4+2];
      const float4 c3 = ((const float4*)sC)[(l+u)*4+3];
      const float cc[DS] = {c0.x,c0.y,c0.z,c0.w, c1.x,c1.y,c1.z,c1.w,
                            c2.x,c2.y,c2.z,c2.w, c3.x,c3.y,c3.z,c3.w};
      float y = 0.f;
#pragma unroll
      for (int n = 0; n < DS; ++n) {
        const float dA = __expf(dtv * A[n]);
        h[n] = fmaf(dA, h[n], dx * bb[n]);
        y = fmaf(h[n], cc[n], y);
      }
      Y[idx + (size_t)u * DM] = fmaf(Dd, xv, y);
    }
    idx += (size_t)4 * DM;
#pragma unroll
    for (int u = 0; u < 4; ++u) { dtb[u] = dtn[u]; xb[u] = xn[u]; }
  }
}

// ---- launch ----
// Workspace (float slots):
//   DTb : MT*DM bf16   = 4194304
//   BP  : MT*DS        =  131072
//   CP  : MT*DS        =  131072
//   Xb  : MT*DM bf16   = 4194304
//   Wx  : 1088*DM bf16 =  278528
//   SD  : BB*NC*DM     =  262144
//   HP  : BB*NC*DM*DS  = 4194304   (becomes Hin in-place after combine)
// total = 13,385,728 floats = 53,542,912 bytes.
extern "C" void kernel_launch(void* const* d_in, const int* in_sizes, int n_in,
                              void* d_out, int out_size, void* d_ws, size_t ws_size,
                              hipStream_t stream)
{
  const float* x     = (const float*)d_in[0];
  const float* W_dt  = (const float*)d_in[1];
  const float* b_dt  = (const float*)d_in[2];
  const float* W_B   = (const float*)d_in[3];
  const float* W_C   = (const float*)d_in[4];
  const float* A_log = (const float*)d_in[5];
  const float* Dv    = (const float*)d_in[6];
  float* Y  = (float*)d_out;
  float* ws = (float*)d_ws;

  __hip_bfloat16* DTb = (__hip_bfloat16*)ws;
  float* BP = ws + (size_t)MT * DM / 2;
  float* CP = BP + (size_t)MT * DS;
  __hip_bfloat16* Xb = (__hip_bfloat16*)(CP + (size_t)MT * DS);
  __hip_bfloat16* Wx = (__hip_bfloat16*)(CP + (size_t)MT * DS + (size_t)MT * DM / 2);
  float* SD = CP + (size_t)MT * DS + (size_t)MT * DM / 2 + (size_t)1088 * DM / 2;
  float* HP = SD + (size_t)BB * NC * DM;

  convert_kernel<<<4640, 256, 0, stream>>>(x, W_dt, W_B, W_C, Xb, Wx);
  gemm_dt_mfma<<<1088, 256, 0, stream>>>(Xb, Wx, b_dt, DTb, BP, CP);
  scan_partial_kernel<<<dim3(DM / 256, NC, BB), 256, 0, stream>>>(DTb, Xb, BP, A_log, SD, HP);
  combine_kernel<<<(BB * DM * DS) / 256, 256, 0, stream>>>(SD, A_log, HP);
  scan_final_kernel<<<dim3(DM / 256, NC, BB), 256, 0, stream>>>(DTb, Xb, BP, CP, A_log, Dv, HP, Y);
}